// Round 1
// 419.308 us; speedup vs baseline: 1.0048x; 1.0048x over previous
//
#include <hip/hip_runtime.h>

// RSTDP update, algebraically reduced:
//   mask[o][i] = post_sp[o]>0.5 && pre_sp[i]>0.5
//   where mask holds, dts = current_time - current_time = 0  ->  dw = -A_MINUS
//   out = clip(weight + reward * dw * mask, -1, 1)
// Pure streaming op: 256 MiB read + 256 MiB write, memory-bound.
// Polish pass: non-temporal (nt) load/store on the touch-once 512 MiB stream
// (both streams > 256 MiB LLC, caching them is pure churn), and block-uniform
// post[] indexing so the spike load scalarizes to an s_load broadcast.

#define N_IN  8192
#define N_OUT 8192
#define A_MINUS 0.012f

typedef float f32x4 __attribute__((ext_vector_type(4)));

__global__ __launch_bounds__(256) void rstdp_kernel(
    const f32x4* __restrict__ w,      // weight, (N_OUT*N_IN/4) float4
    const f32x4* __restrict__ pre,    // pre_spikes  (N_IN/4 float4)
    const float* __restrict__ post,   // post_spikes (N_OUT)
    const float* __restrict__ reward, // scalar
    f32x4* __restrict__ out)
{
    // 8192/4 = 2048 float4 per row; 256-thread blocks -> 8 blocks per row.
    const unsigned row  = blockIdx.x >> 3;                        // block-uniform
    const unsigned col4 = ((blockIdx.x & 7u) << 8) | threadIdx.x; // 0..2047
    const unsigned gid  = (row << 11) | col4;

    const float rdelta  = reward[0] * (-A_MINUS);  // uniform
    const bool post_act = post[row] > 0.5f;        // uniform index -> scalar load

    const f32x4 pre4 = pre[col4];                  // 32 KB vector, cache-resident
    f32x4 wv = __builtin_nontemporal_load(&w[gid]);

    const float d0 = (post_act && pre4.x > 0.5f) ? rdelta : 0.0f;
    const float d1 = (post_act && pre4.y > 0.5f) ? rdelta : 0.0f;
    const float d2 = (post_act && pre4.z > 0.5f) ? rdelta : 0.0f;
    const float d3 = (post_act && pre4.w > 0.5f) ? rdelta : 0.0f;

    wv.x = fminf(fmaxf(wv.x + d0, -1.0f), 1.0f);   // folds to v_med3_f32
    wv.y = fminf(fmaxf(wv.y + d1, -1.0f), 1.0f);
    wv.z = fminf(fmaxf(wv.z + d2, -1.0f), 1.0f);
    wv.w = fminf(fmaxf(wv.w + d3, -1.0f), 1.0f);

    __builtin_nontemporal_store(wv, &out[gid]);
}

extern "C" void kernel_launch(void* const* d_in, const int* in_sizes, int n_in,
                              void* d_out, int out_size, void* d_ws, size_t ws_size,
                              hipStream_t stream) {
    // Inputs in setup_inputs() order:
    // 0: weight (N_OUT*N_IN f32), 1: pre_spikes (N_IN), 2: post_spikes (N_OUT),
    // 3: reward (1), 4: pre_times (N_IN, unused), 5: post_times (N_OUT, unused)
    const f32x4* w      = (const f32x4*)d_in[0];
    const f32x4* pre    = (const f32x4*)d_in[1];
    const float* post   = (const float*)d_in[2];
    const float* reward = (const float*)d_in[3];
    f32x4* out = (f32x4*)d_out;

    const int total4 = (N_OUT * N_IN) / 4;   // 16,777,216
    const int block  = 256;
    const int grid   = total4 / block;       // 65,536 blocks = 8192 rows x 8

    rstdp_kernel<<<grid, block, 0, stream>>>(w, pre, post, reward, out);
}